// Round 5
// baseline (49.548 us; speedup 1.0000x reference)
//
#include <hip/hip_runtime.h>

typedef unsigned long long u64;

#define N_ROIS 2048
#define N_CLSX 21
#define N_CLS_OUT 20
#define SCORE_T 0.3f
#define NMS_T 0.3f
#define DEDUP_T 0.3f
#define NT 256
#define NWAVES (NT / 64)
#define CPW (N_ROIS / 64 / NWAVES)
#define NVMAX 512
#define NWMAX (NVMAX / 64)

// ---- d_ws byte offsets (ws is ~268MB; we use <3MB) ----
#define OFF_SBOX   0                                  // float4 [20][2048]
#define OFF_SSC    (20 * 2048 * 16)                   // float  [20][2048]
#define OFF_NV     (OFF_SSC + 20 * 2048 * 4)          // int    [20]
#define OFF_SUP    (OFF_NV + 4096)                    // u64    [20][512][8]
#define OFF_KW     (OFF_SUP + 20 * 512 * 8 * 8)       // u64    [20][8]
#define OFF_KEEPB  (OFF_KW + 20 * 8 * 8)              // u8     [20][2048]

// ============ K1: stage scores, compact, rank, decode -> ws ============
__global__ __launch_bounds__(NT) void prep_kernel(
    const float* __restrict__ rois,
    const float* __restrict__ cls_prob,
    const float* __restrict__ bbox_pred,
    const float* __restrict__ im_info,
    char* __restrict__ ws)
{
    __shared__ float lsc[N_ROIS];
    __shared__ float vsc[N_ROIS];
    __shared__ int   vidx[N_ROIS];
    __shared__ int   wbase[NWAVES];

    const int tid = threadIdx.x;
    const int wid = tid >> 6, lane = tid & 63;
    const int bx = blockIdx.x;
    const int cls = bx + 1;

    float4* sboxws = (float4*)(ws + OFF_SBOX) + bx * N_ROIS;
    float*  sscws  = (float*)(ws + OFF_SSC) + bx * N_ROIS;
    int*    nvws   = (int*)(ws + OFF_NV);

    for (int t = tid; t < N_ROIS; t += NT) lsc[t] = cls_prob[t * N_CLSX + cls];
    __syncthreads();

    // compaction pass 1: per-wave valid masks
    u64 masks[CPW];
    int mycnt = 0;
    #pragma unroll
    for (int c = 0; c < CPW; ++c) {
        int i = ((wid * CPW + c) << 6) + lane;
        masks[c] = __ballot(lsc[i] > SCORE_T);
        mycnt += __popcll(masks[c]);
    }
    if (lane == 0) wbase[wid] = mycnt;
    __syncthreads();
    int base = 0;
    for (int w = 0; w < wid; ++w) base += wbase[w];
    int nvtot = 0;
    for (int w = 0; w < NWAVES; ++w) nvtot += wbase[w];
    const int nv = nvtot;

    // compaction pass 2: ordered scatter
    #pragma unroll
    for (int c = 0; c < CPW; ++c) {
        int i = ((wid * CPW + c) << 6) + lane;
        u64 m = masks[c];
        if ((m >> lane) & 1ULL) {
            int pre = __popcll(m & ((1ULL << lane) - 1ULL));
            vidx[base + pre] = i;
            vsc[base + pre]  = lsc[i];
        }
        base += __popcll(m);
    }
    __syncthreads();

    // rank + decode valid boxes, scatter to ws in sorted order
    const float W = im_info[1], H = im_info[0];
    for (int v = tid; v < nv; v += NT) {
        float sc = vsc[v];
        int r = 0;
        for (int u = 0; u < nv; ++u) {
            float su = vsc[u];
            r += (su > sc) || (su == sc && u < v);
        }
        int idx = vidx[v];
        float x1 = rois[idx * 5 + 1], y1 = rois[idx * 5 + 2];
        float x2 = rois[idx * 5 + 3], y2 = rois[idx * 5 + 4];
        float w = x2 - x1 + 1.0f, h = y2 - y1 + 1.0f;
        float cx = x1 + 0.5f * w, cy = y1 + 0.5f * h;
        const float* d = &bbox_pred[idx * 84 + cls * 4];
        float dx = d[0] * 0.1f, dy = d[1] * 0.1f;
        float dw = d[2] * 0.2f, dh = d[3] * 0.2f;
        float pcx = dx * w + cx, pcy = dy * h + cy;
        float pw = expf(dw) * w, ph = expf(dh) * h;
        float4 b;
        b.x = fminf(fmaxf(pcx - 0.5f * pw, 0.0f), W - 1.0f);
        b.y = fminf(fmaxf(pcy - 0.5f * ph, 0.0f), H - 1.0f);
        b.z = fminf(fmaxf(pcx + 0.5f * pw, 0.0f), W - 1.0f);
        b.w = fminf(fmaxf(pcy + 0.5f * ph, 0.0f), H - 1.0f);
        sboxws[r] = b;
        sscws[r]  = sc;
    }
    if (tid == 0) nvws[bx] = nv;
}

// ============ K2: suppression bit-matrix -> ws ============
__global__ __launch_bounds__(NT) void bitmat_kernel(char* __restrict__ ws)
{
    __shared__ float4 sbox[NVMAX];
    const int tid = threadIdx.x;
    const int wid = tid >> 6, lane = tid & 63;
    const int bx = blockIdx.x;

    const int nv = ((const int*)(ws + OFF_NV))[bx];
    if (nv > NVMAX || nv == 0) return;

    const float4* sboxws = (const float4*)(ws + OFF_SBOX) + bx * N_ROIS;
    u64* sup = (u64*)(ws + OFF_SUP) + (size_t)bx * NVMAX * NWMAX;

    for (int t = tid; t < nv; t += NT) sbox[t] = sboxws[t];
    __syncthreads();

    const int NW = (nv + 63) >> 6;
    for (int task = wid; task < nv * NW; task += NWAVES) {
        int i = task / NW;
        int w = task - i * NW;
        float4 a = sbox[i];
        float aarea = (a.z - a.x) * (a.w - a.y);
        int j = (w << 6) + lane;
        bool bit = false;
        if (j < nv && j > i) {
            float4 bb = sbox[j];
            float ix1 = fmaxf(a.x, bb.x), iy1 = fmaxf(a.y, bb.y);
            float ix2 = fminf(a.z, bb.z), iy2 = fminf(a.w, bb.w);
            float iw = fmaxf(ix2 - ix1, 0.0f), ih = fmaxf(iy2 - iy1, 0.0f);
            float inter = iw * ih;
            float barea = (bb.z - bb.x) * (bb.w - bb.y);
            bit = inter / (aarea + barea - inter + 1e-6f) > NMS_T;
        }
        u64 wd = __ballot(bit);
        if (lane == 0) sup[i * NWMAX + w] = wd;
    }
}

// ============ K3: greedy reduction -> kw words (or keepb fallback) ============
__global__ __launch_bounds__(64) void greedy_kernel(char* __restrict__ ws)
{
    const int bx = blockIdx.x;
    const int lane = threadIdx.x;
    const int nv = ((const int*)(ws + OFF_NV))[bx];

    u64* kwws = (u64*)(ws + OFF_KW) + bx * NWMAX;

    if (nv <= NVMAX) {
        const u64* sup = (const u64*)(ws + OFF_SUP) + (size_t)bx * NVMAX * NWMAX;
        #define INITKW(W_) ((nv > (W_)*64) \
            ? ((nv - (W_)*64 >= 64) ? ~0ULL : ((1ULL << (nv - (W_)*64)) - 1ULL)) \
            : 0ULL)
        u64 kw0 = INITKW(0), kw1 = INITKW(1), kw2 = INITKW(2), kw3 = INITKW(3),
            kw4 = INITKW(4), kw5 = INITKW(5), kw6 = INITKW(6), kw7 = INITKW(7);
        #define PROC_WORD(KWW, WB)                                        \
        {                                                                 \
            int lim = nv - (WB); lim = lim > 64 ? 64 : lim;               \
            for (int b = 0; b < lim; ++b) {                               \
                if ((KWW >> b) & 1ULL) {                                  \
                    const u64* row = &sup[((WB) + b) * NWMAX];            \
                    kw0 &= ~row[0]; kw1 &= ~row[1];                       \
                    kw2 &= ~row[2]; kw3 &= ~row[3];                       \
                    kw4 &= ~row[4]; kw5 &= ~row[5];                       \
                    kw6 &= ~row[6]; kw7 &= ~row[7];                       \
                }                                                         \
            }                                                             \
        }
        PROC_WORD(kw0, 0);
        if (nv > 64)  PROC_WORD(kw1, 64);
        if (nv > 128) PROC_WORD(kw2, 128);
        if (nv > 192) PROC_WORD(kw3, 192);
        if (nv > 256) PROC_WORD(kw4, 256);
        if (nv > 320) PROC_WORD(kw5, 320);
        if (nv > 384) PROC_WORD(kw6, 384);
        if (nv > 448) PROC_WORD(kw7, 448);
        if (lane == 0) {
            kwws[0] = kw0; kwws[1] = kw1; kwws[2] = kw2; kwws[3] = kw3;
            kwws[4] = kw4; kwws[5] = kw5; kwws[6] = kw6; kwws[7] = kw7;
        }
    } else {
        // fallback: O(nv^2) greedy on one wave, boxes staged in LDS
        __shared__ float4 sbox[N_ROIS];
        __shared__ unsigned char keepb[N_ROIS];
        const float4* sboxws = (const float4*)(ws + OFF_SBOX) + bx * N_ROIS;
        unsigned char* keepbws = (unsigned char*)(ws + OFF_KEEPB) + bx * N_ROIS;
        for (int t = lane; t < nv; t += 64) { sbox[t] = sboxws[t]; keepb[t] = 1; }
        __syncthreads();
        for (int i = 0; i < nv; ++i) {
            __syncthreads();
            if (keepb[i]) {
                float4 a = sbox[i];
                float aarea = (a.z - a.x) * (a.w - a.y);
                for (int j = i + 1 + lane; j < nv; j += 64) {
                    if (keepb[j]) {
                        float4 bb = sbox[j];
                        float ix1 = fmaxf(a.x, bb.x), iy1 = fmaxf(a.y, bb.y);
                        float ix2 = fminf(a.z, bb.z), iy2 = fminf(a.w, bb.w);
                        float iw = fmaxf(ix2 - ix1, 0.0f), ih = fmaxf(iy2 - iy1, 0.0f);
                        float inter = iw * ih;
                        float barea = (bb.z - bb.x) * (bb.w - bb.y);
                        if (inter / (aarea + barea - inter + 1e-6f) > NMS_T)
                            keepb[j] = 0;
                    }
                }
            }
        }
        __syncthreads();
        for (int t = lane; t < nv; t += 64) keepbws[t] = keepb[t];
    }
}

// ============ K4: GT dedup + coalesced output write ============
__global__ __launch_bounds__(NT) void finish_kernel(
    char* __restrict__ ws,
    const float* __restrict__ gt_boxes,
    const int* __restrict__ num_boxes,
    float* __restrict__ out)
{
    __shared__ float4 sbox[N_ROIS];
    __shared__ float  ssc[N_ROIS];
    __shared__ unsigned char keepb[N_ROIS];
    __shared__ float4 sgt[64];

    const int tid = threadIdx.x;
    const int bx = blockIdx.x;
    const int ng = *num_boxes;
    const int nv = ((const int*)(ws + OFF_NV))[bx];

    const float4* sboxws = (const float4*)(ws + OFF_SBOX) + bx * N_ROIS;
    const float*  sscws  = (const float*)(ws + OFF_SSC) + bx * N_ROIS;
    const u64*    kwws   = (const u64*)(ws + OFF_KW) + bx * NWMAX;
    const unsigned char* keepbws = (const unsigned char*)(ws + OFF_KEEPB) + bx * N_ROIS;

    for (int t = tid; t < nv; t += NT) { sbox[t] = sboxws[t]; ssc[t] = sscws[t]; }
    for (int g = tid; g < ng; g += NT)
        sgt[g] = make_float4(gt_boxes[g * 5 + 0], gt_boxes[g * 5 + 1],
                             gt_boxes[g * 5 + 2], gt_boxes[g * 5 + 3]);
    __syncthreads();

    for (int v = tid; v < nv; v += NT) {
        bool kept = (nv <= NVMAX)
                        ? (bool)((kwws[v >> 6] >> (v & 63)) & 1ULL)
                        : (bool)keepbws[v];
        if (kept) {
            float4 a = sbox[v];
            float aarea = (a.z - a.x) * (a.w - a.y);
            for (int g = 0; g < ng; ++g) {
                float4 gb = sgt[g];
                float ix1 = fmaxf(a.x, gb.x), iy1 = fmaxf(a.y, gb.y);
                float ix2 = fminf(a.z, gb.z), iy2 = fminf(a.w, gb.w);
                float iw = fmaxf(ix2 - ix1, 0.0f), ih = fmaxf(iy2 - iy1, 0.0f);
                float inter = iw * ih;
                float garea = (gb.z - gb.x) * (gb.w - gb.y);
                if (inter / (aarea + garea - inter + 1e-6f) > DEDUP_T) {
                    kept = false; break;
                }
            }
        }
        keepb[v] = kept ? 1 : 0;
    }
    __syncthreads();

    float* o = out + (size_t)bx * N_ROIS * 5;
    for (int t = tid; t < N_ROIS * 5; t += NT) {
        int j = t / 5, comp = t - 5 * j;
        float val = 0.0f;
        if (j < nv && keepb[j]) {
            float4 b = sbox[j];
            val = comp == 0 ? b.x : comp == 1 ? b.y : comp == 2 ? b.z :
                  comp == 3 ? b.w : ssc[j];
        }
        o[t] = val;
    }
}

extern "C" void kernel_launch(void* const* d_in, const int* in_sizes, int n_in,
                              void* d_out, int out_size, void* d_ws, size_t ws_size,
                              hipStream_t stream) {
    const float* rois      = (const float*)d_in[0];
    const float* cls_prob  = (const float*)d_in[1];
    const float* bbox_pred = (const float*)d_in[2];
    const float* im_info   = (const float*)d_in[3];
    const float* gt        = (const float*)d_in[4];
    const int*   nb        = (const int*)d_in[5];
    float* out = (float*)d_out;
    char*  ws  = (char*)d_ws;

    prep_kernel<<<dim3(N_CLS_OUT), dim3(NT), 0, stream>>>(
        rois, cls_prob, bbox_pred, im_info, ws);
    bitmat_kernel<<<dim3(N_CLS_OUT), dim3(NT), 0, stream>>>(ws);
    greedy_kernel<<<dim3(N_CLS_OUT), dim3(64), 0, stream>>>(ws);
    finish_kernel<<<dim3(N_CLS_OUT), dim3(NT), 0, stream>>>(ws, gt, nb, out);
}

// Round 6
// 42.808 us; speedup vs baseline: 1.1574x; 1.1574x over previous
//
#include <hip/hip_runtime.h>

typedef unsigned long long u64;

#define N_ROIS 2048
#define N_CLSX 21
#define N_CLS_OUT 20
#define SCORE_T 0.3f
#define NMS_T 0.3f
#define DEDUP_T 0.3f
#define NT 256
#define NWAVES (NT / 64)
#define CPW (N_ROIS / 64 / NWAVES)   // 8 chunks of 64 rois per wave
#define NVMAX 512
#define NWMAX (NVMAX / 64)           // 8 keep-mask words

__global__ __launch_bounds__(NT) void detect_kernel(
    const float* __restrict__ rois,      // (2048,5)
    const float* __restrict__ cls_prob,  // (2048,21)
    const float* __restrict__ bbox_pred, // (2048,84)
    const float* __restrict__ im_info,   // (3,)
    const float* __restrict__ gt_boxes,  // (50,5)
    const int*   __restrict__ num_boxes,
    float* __restrict__ out)             // (20,2048,5)
{
    __shared__ float  vsc[N_ROIS];
    __shared__ int    vidx[N_ROIS];
    __shared__ float4 sbox[N_ROIS];          // sorted decoded boxes
    __shared__ float  ssc[N_ROIS];           // sorted scores
    __shared__ u64    supmat[NVMAX * NWMAX]; // row-stride NWMAX
    __shared__ u64    dupw[NWMAX];           // GT-dedup bit words
    __shared__ unsigned char keepb[N_ROIS];  // fallback only
    __shared__ float4 sgt[64];
    __shared__ int    wbase[NWAVES];

    const int tid = threadIdx.x;
    const int wid = tid >> 6, lane = tid & 63;
    const int cls = blockIdx.x + 1;
    const int ng = *num_boxes;
    const float W = im_info[1], H = im_info[0];

    // ---- gt staging (no barrier needed until phase 3 consumes it)
    for (int g = tid; g < ng; g += NT)
        sgt[g] = make_float4(gt_boxes[g * 5 + 0], gt_boxes[g * 5 + 1],
                             gt_boxes[g * 5 + 2], gt_boxes[g * 5 + 3]);

    // ---- phase 1: compact straight from global (independent strided loads)
    u64 masks[CPW];
    float vals[CPW];
    int mycnt = 0;
    #pragma unroll
    for (int c = 0; c < CPW; ++c) {
        int i = ((wid * CPW + c) << 6) + lane;
        float sc = cls_prob[i * N_CLSX + cls];
        vals[c] = sc;
        masks[c] = __ballot(sc > SCORE_T);
        mycnt += __popcll(masks[c]);
    }
    if (lane == 0) wbase[wid] = mycnt;
    __syncthreads();                               // B1
    int base = 0;
    for (int w = 0; w < wid; ++w) base += wbase[w];
    int nvtot = 0;
    for (int w = 0; w < NWAVES; ++w) nvtot += wbase[w];
    const int nv = nvtot;
    #pragma unroll
    for (int c = 0; c < CPW; ++c) {
        int i = ((wid * CPW + c) << 6) + lane;
        u64 m = masks[c];
        if ((m >> lane) & 1ULL) {
            int pre = __popcll(m & ((1ULL << lane) - 1ULL));
            vidx[base + pre] = i;
            vsc[base + pre]  = vals[c];
        }
        base += __popcll(m);
    }
    __syncthreads();                               // B2

    // ---- phase 2: rank (score desc, roi asc) + decode, scatter sorted
    for (int v = tid; v < nv; v += NT) {
        int idx = vidx[v];
        // issue global gathers up front; they overlap the rank scan below
        float x1 = rois[idx * 5 + 1], y1 = rois[idx * 5 + 2];
        float x2 = rois[idx * 5 + 3], y2 = rois[idx * 5 + 4];
        const float* dp = &bbox_pred[idx * 84 + cls * 4];
        float d0 = dp[0], d1 = dp[1], d2 = dp[2], d3 = dp[3];
        float sc = vsc[v];
        int r = 0;
        for (int u = 0; u < nv; ++u) {
            float su = vsc[u];
            r += (su > sc) || (su == sc && u < v);
        }
        float w = x2 - x1 + 1.0f, h = y2 - y1 + 1.0f;
        float cx = x1 + 0.5f * w, cy = y1 + 0.5f * h;
        float dx = d0 * 0.1f, dy = d1 * 0.1f;
        float dw = d2 * 0.2f, dh = d3 * 0.2f;
        float pcx = dx * w + cx, pcy = dy * h + cy;
        float pw = expf(dw) * w, ph = expf(dh) * h;
        float4 b;
        b.x = fminf(fmaxf(pcx - 0.5f * pw, 0.0f), W - 1.0f);
        b.y = fminf(fmaxf(pcy - 0.5f * ph, 0.0f), H - 1.0f);
        b.z = fminf(fmaxf(pcx + 0.5f * pw, 0.0f), W - 1.0f);
        b.w = fminf(fmaxf(pcy + 0.5f * ph, 0.0f), H - 1.0f);
        sbox[r] = b;
        ssc[r]  = sc;
    }
    __syncthreads();                               // B3

    const int NW = (nv + 63) >> 6;

    // ---- phase 3: suppression bit-matrix + GT-dup words (branch-free tasks)
    if (nv <= NVMAX) {
        const int ntask = nv * NW;
        for (int task = wid; task < ntask + NW; task += NWAVES) {
            if (task < ntask) {
                int i = task / NW;
                int w = task - i * NW;
                float4 a = sbox[i];
                float aarea = (a.z - a.x) * (a.w - a.y);
                int j = (w << 6) + lane;
                bool bit = false;
                if (j < nv && j > i) {
                    float4 bb = sbox[j];
                    float ix1 = fmaxf(a.x, bb.x), iy1 = fmaxf(a.y, bb.y);
                    float ix2 = fminf(a.z, bb.z), iy2 = fminf(a.w, bb.w);
                    float iw = fmaxf(ix2 - ix1, 0.0f), ih = fmaxf(iy2 - iy1, 0.0f);
                    float inter = iw * ih;
                    float barea = (bb.z - bb.x) * (bb.w - bb.y);
                    bit = inter / (aarea + barea - inter + 1e-6f) > NMS_T;
                }
                u64 wd = __ballot(bit);
                if (lane == 0) supmat[i * NWMAX + w] = wd;
            } else {
                int w = task - ntask;
                int j = (w << 6) + lane;
                bool dup = false;
                if (j < nv) {
                    float4 a = sbox[j];
                    float aarea = (a.z - a.x) * (a.w - a.y);
                    for (int g = 0; g < ng; ++g) {      // no break: pipelined
                        float4 gb = sgt[g];
                        float ix1 = fmaxf(a.x, gb.x), iy1 = fmaxf(a.y, gb.y);
                        float ix2 = fminf(a.z, gb.z), iy2 = fminf(a.w, gb.w);
                        float iw = fmaxf(ix2 - ix1, 0.0f), ih = fmaxf(iy2 - iy1, 0.0f);
                        float inter = iw * ih;
                        float garea = (gb.z - gb.x) * (gb.w - gb.y);
                        dup |= inter / (aarea + garea - inter + 1e-6f) > DEDUP_T;
                    }
                }
                u64 wd = __ballot(dup);
                if (lane == 0) dupw[w] = wd;
            }
        }
    }
    __syncthreads();                               // B4

    float* o = out + (size_t)blockIdx.x * N_ROIS * 5;

    if (nv <= NVMAX) {
        // ---- phase 4: greedy reduction, loads decoupled from the bit chain.
        // Blocked forward-substitution: resolve diagonal word (4-deep
        // prefetch), apply row to later words with mask ap = -(bit).
        #define INITKW(W_) ((nv > (W_)*64) \
            ? ((nv - (W_)*64 >= 64) ? ~0ULL : ((1ULL << (nv - (W_)*64)) - 1ULL)) \
            : 0ULL)
        u64 kw0 = INITKW(0), kw1 = INITKW(1), kw2 = INITKW(2), kw3 = INITKW(3),
            kw4 = INITKW(4), kw5 = INITKW(5), kw6 = INITKW(6), kw7 = INITKW(7);

        #define APPL(C, B, AP)                                                \
        {                                                                     \
            const u64* _r = &supmat[(bbase + (B)) * NWMAX];                   \
            if ((C) < 1) kw1 &= ~(_r[1] & (AP));                              \
            if ((C) < 2) kw2 &= ~(_r[2] & (AP));                              \
            if ((C) < 3) kw3 &= ~(_r[3] & (AP));                              \
            if ((C) < 4) kw4 &= ~(_r[4] & (AP));                              \
            if ((C) < 5) kw5 &= ~(_r[5] & (AP));                              \
            if ((C) < 6) kw6 &= ~(_r[6] & (AP));                              \
            if ((C) < 7) kw7 &= ~(_r[7] & (AP));                              \
        }
        #define STEP(C, KWc)                                                  \
        if (nv > (C) * 64) {                                                  \
            const int bbase = (C) * 64;                                       \
            int lim = nv - bbase; if (lim > 64) lim = 64;                     \
            u64 n0 = supmat[(bbase + 0) * NWMAX + (C)];                       \
            u64 n1 = supmat[(bbase + 1) * NWMAX + (C)];                       \
            u64 n2 = supmat[(bbase + 2) * NWMAX + (C)];                       \
            u64 n3 = supmat[(bbase + 3) * NWMAX + (C)];                       \
            int b = 0;                                                        \
            for (; b + 4 <= lim; b += 4) {                                    \
                u64 c0 = n0, c1 = n1, c2 = n2, c3 = n3;                       \
                n0 = supmat[(bbase + b + 4) * NWMAX + (C)];                   \
                n1 = supmat[(bbase + b + 5) * NWMAX + (C)];                   \
                n2 = supmat[(bbase + b + 6) * NWMAX + (C)];                   \
                n3 = supmat[(bbase + b + 7) * NWMAX + (C)];                   \
                u64 a0 = 0ULL - ((KWc >> (b + 0)) & 1ULL);                    \
                KWc &= ~(c0 & a0); APPL(C, b + 0, a0);                        \
                u64 a1 = 0ULL - ((KWc >> (b + 1)) & 1ULL);                    \
                KWc &= ~(c1 & a1); APPL(C, b + 1, a1);                        \
                u64 a2 = 0ULL - ((KWc >> (b + 2)) & 1ULL);                    \
                KWc &= ~(c2 & a2); APPL(C, b + 2, a2);                        \
                u64 a3 = 0ULL - ((KWc >> (b + 3)) & 1ULL);                    \
                KWc &= ~(c3 & a3); APPL(C, b + 3, a3);                        \
            }                                                                 \
            for (; b < lim; ++b) {                                            \
                u64 r = supmat[(bbase + b) * NWMAX + (C)];                    \
                u64 ap = 0ULL - ((KWc >> b) & 1ULL);                          \
                KWc &= ~(r & ap); APPL(C, b, ap);                             \
            }                                                                 \
        }
        STEP(0, kw0) STEP(1, kw1) STEP(2, kw2) STEP(3, kw3)
        STEP(4, kw4) STEP(5, kw5) STEP(6, kw6) STEP(7, kw7)

        // apply GT-dup words (kw_k for k>=NW are 0, so unguarded is safe)
        kw0 &= ~dupw[0]; kw1 &= ~dupw[1]; kw2 &= ~dupw[2]; kw3 &= ~dupw[3];
        kw4 &= ~dupw[4]; kw5 &= ~dupw[5]; kw6 &= ~dupw[6]; kw7 &= ~dupw[7];

        // ---- phase 5: write straight from register keep-words
        for (int t = tid; t < N_ROIS * 5; t += NT) {
            int j = t / 5, comp = t - 5 * j;
            int wsel = j >> 6;
            u64 myw = wsel == 0 ? kw0 : wsel == 1 ? kw1 : wsel == 2 ? kw2 :
                      wsel == 3 ? kw3 : wsel == 4 ? kw4 : wsel == 5 ? kw5 :
                      wsel == 6 ? kw6 : wsel == 7 ? kw7 : 0ULL;
            float val = 0.0f;
            if (j < nv && ((myw >> (j & 63)) & 1ULL)) {
                float4 b = sbox[j];
                val = comp == 0 ? b.x : comp == 1 ? b.y : comp == 2 ? b.z :
                      comp == 3 ? b.w : ssc[j];
            }
            o[t] = val;
        }
    } else {
        // ---- fallback (nv > NVMAX): barrier-per-row greedy (correctness)
        for (int t = tid; t < nv; t += NT) keepb[t] = 1;
        for (int i = 0; i < nv; ++i) {
            __syncthreads();
            if (keepb[i]) {
                float4 a = sbox[i];
                float aarea = (a.z - a.x) * (a.w - a.y);
                for (int j = i + 1 + tid; j < nv; j += NT) {
                    if (keepb[j]) {
                        float4 bb = sbox[j];
                        float ix1 = fmaxf(a.x, bb.x), iy1 = fmaxf(a.y, bb.y);
                        float ix2 = fminf(a.z, bb.z), iy2 = fminf(a.w, bb.w);
                        float iw = fmaxf(ix2 - ix1, 0.0f), ih = fmaxf(iy2 - iy1, 0.0f);
                        float inter = iw * ih;
                        float barea = (bb.z - bb.x) * (bb.w - bb.y);
                        if (inter / (aarea + barea - inter + 1e-6f) > NMS_T)
                            keepb[j] = 0;
                    }
                }
            }
        }
        __syncthreads();
        for (int v = tid; v < nv; v += NT) {
            bool kept = keepb[v] != 0;
            if (kept) {
                float4 a = sbox[v];
                float aarea = (a.z - a.x) * (a.w - a.y);
                bool dup = false;
                for (int g = 0; g < ng; ++g) {
                    float4 gb = sgt[g];
                    float ix1 = fmaxf(a.x, gb.x), iy1 = fmaxf(a.y, gb.y);
                    float ix2 = fminf(a.z, gb.z), iy2 = fminf(a.w, gb.w);
                    float iw = fmaxf(ix2 - ix1, 0.0f), ih = fmaxf(iy2 - iy1, 0.0f);
                    float inter = iw * ih;
                    float garea = (gb.z - gb.x) * (gb.w - gb.y);
                    dup |= inter / (aarea + garea - inter + 1e-6f) > DEDUP_T;
                }
                kept = !dup;
            }
            keepb[v] = kept ? 1 : 0;
        }
        __syncthreads();
        for (int t = tid; t < N_ROIS * 5; t += NT) {
            int j = t / 5, comp = t - 5 * j;
            float val = 0.0f;
            if (j < nv && keepb[j]) {
                float4 b = sbox[j];
                val = comp == 0 ? b.x : comp == 1 ? b.y : comp == 2 ? b.z :
                      comp == 3 ? b.w : ssc[j];
            }
            o[t] = val;
        }
    }
}

extern "C" void kernel_launch(void* const* d_in, const int* in_sizes, int n_in,
                              void* d_out, int out_size, void* d_ws, size_t ws_size,
                              hipStream_t stream) {
    const float* rois      = (const float*)d_in[0];
    const float* cls_prob  = (const float*)d_in[1];
    const float* bbox_pred = (const float*)d_in[2];
    const float* im_info   = (const float*)d_in[3];
    const float* gt        = (const float*)d_in[4];
    const int*   nb        = (const int*)d_in[5];
    float* out = (float*)d_out;

    detect_kernel<<<dim3(N_CLS_OUT), dim3(NT), 0, stream>>>(
        rois, cls_prob, bbox_pred, im_info, gt, nb, out);
}

// Round 7
// 41.857 us; speedup vs baseline: 1.1837x; 1.0227x over previous
//
#include <hip/hip_runtime.h>

typedef unsigned long long u64;

#define N_ROIS 2048
#define N_CLSX 21
#define N_CLS_OUT 20
#define SCORE_T 0.3f
#define NMS_T 0.3f
#define DEDUP_T 0.3f
#define NT 256
#define NWAVES (NT / 64)
#define CPW (N_ROIS / 64 / NWAVES)   // 8 chunks of 64 rois per wave
#define NFAST 128                    // register-path bound (2 slots/lane)
#define NVMAX 512
#define NWMAX (NVMAX / 64)

__device__ __forceinline__ float iou_f(float ax1, float ay1, float ax2, float ay2,
                                       float aarea,
                                       float bx1, float by1, float bx2, float by2,
                                       float barea) {
    float ix1 = fmaxf(ax1, bx1), iy1 = fmaxf(ay1, by1);
    float ix2 = fminf(ax2, bx2), iy2 = fminf(ay2, by2);
    float iw = fmaxf(ix2 - ix1, 0.0f), ih = fmaxf(iy2 - iy1, 0.0f);
    float inter = iw * ih;
    return inter / (aarea + barea - inter + 1e-6f);
}

__global__ __launch_bounds__(NT) void detect_kernel(
    const float* __restrict__ rois,      // (2048,5)
    const float* __restrict__ cls_prob,  // (2048,21)
    const float* __restrict__ bbox_pred, // (2048,84)
    const float* __restrict__ im_info,   // (3,)
    const float* __restrict__ gt_boxes,  // (50,5)
    const int*   __restrict__ num_boxes,
    float* __restrict__ out)             // (20,2048,5)
{
    __shared__ float  vsc[N_ROIS];
    __shared__ int    vidx[N_ROIS];
    __shared__ float4 sbox[N_ROIS];
    __shared__ float  ssc[N_ROIS];
    __shared__ u64    supmat[NVMAX * NWMAX];   // fallback only
    __shared__ u64    dupw[NWMAX];
    __shared__ unsigned char keepb[N_ROIS];    // deep-fallback only
    __shared__ float4 sgt[64];
    __shared__ int    wbase[NWAVES];
    __shared__ float  rsc[NFAST];
    __shared__ int    ridx[NFAST];
    __shared__ u64    kwords[2];

    const int tid = threadIdx.x;
    const int wid = tid >> 6, lane = tid & 63;
    const int cls = blockIdx.x + 1;
    const int ng = *num_boxes;
    const float W = im_info[1], H = im_info[0];
    float* o = out + (size_t)blockIdx.x * N_ROIS * 5;

    // ---- phase 1: compact straight from global (independent strided loads)
    u64 masks[CPW];
    float vals[CPW];
    int mycnt = 0;
    #pragma unroll
    for (int c = 0; c < CPW; ++c) {
        int i = ((wid * CPW + c) << 6) + lane;
        float sc = cls_prob[i * N_CLSX + cls];
        vals[c] = sc;
        masks[c] = __ballot(sc > SCORE_T);
        mycnt += __popcll(masks[c]);
    }
    if (lane == 0) wbase[wid] = mycnt;
    __syncthreads();                               // B1
    int base = 0;
    for (int w = 0; w < wid; ++w) base += wbase[w];
    int nvtot = 0;
    for (int w = 0; w < NWAVES; ++w) nvtot += wbase[w];
    const int nv = nvtot;
    #pragma unroll
    for (int c = 0; c < CPW; ++c) {
        int i = ((wid * CPW + c) << 6) + lane;
        u64 m = masks[c];
        if ((m >> lane) & 1ULL) {
            int pre = __popcll(m & ((1ULL << lane) - 1ULL));
            vidx[base + pre] = i;
            vsc[base + pre]  = vals[c];
        }
        base += __popcll(m);
    }
    __syncthreads();                               // B2

    if (nv <= NFAST) {
        // ================= FAST PATH: one-wave register NMS =================
        float s0 = 0.0f, s1 = 0.0f;
        if (wid == 0) {
            // rank via shfl count-loop (no LDS in the loop)
            s0 = (lane < nv)      ? vsc[lane]      : 0.0f;
            s1 = (64 + lane < nv) ? vsc[64 + lane] : 0.0f;
            int r0 = 0, r1 = 0;
            const int n0 = nv < 64 ? nv : 64;
            for (int u = 0; u < n0; ++u) {
                float su0 = __shfl(s0, u);
                float su1 = __shfl(s1, u);
                r0 += (su0 > s0) || (su0 == s0 && u < lane);
                r1 += (su0 > s1) || (su0 == s1);
                if (64 + u < nv) {
                    r0 += (su1 > s0);
                    r1 += (su1 > s1) || (su1 == s1 && u < lane);
                }
            }
            if (lane < nv)      { rsc[r0] = s0; ridx[r0] = vidx[lane]; }
            if (64 + lane < nv) { rsc[r1] = s1; ridx[r1] = vidx[64 + lane]; }
        } else {
            // waves 1-3: stage gt + zero-fill output with independent stores
            if (wid == 3)
                for (int g = lane; g < ng; g += 64)
                    sgt[g] = make_float4(gt_boxes[g * 5 + 0], gt_boxes[g * 5 + 1],
                                         gt_boxes[g * 5 + 2], gt_boxes[g * 5 + 3]);
            float4* o4 = (float4*)o;                 // 2560 float4 per class
            float4 z4 = make_float4(0.f, 0.f, 0.f, 0.f);
            for (int t = (wid - 1) * 64 + lane; t < N_ROIS * 5 / 4; t += 192)
                o4[t] = z4;
        }
        __syncthreads();                             // B3 (ranked order ready)

        float4 b0 = make_float4(0,0,0,0), b1 = make_float4(0,0,0,0);
        float sc0 = 0.0f, sc1 = 0.0f;
        if (wid == 0) {
            // decode ranked elements (independent gathers)
            int e0 = lane, e1 = 64 + lane;
            int idx0 = (e0 < nv) ? ridx[e0] : 0;
            int idx1 = (e1 < nv) ? ridx[e1] : 0;
            sc0 = (e0 < nv) ? rsc[e0] : 0.0f;
            sc1 = (e1 < nv) ? rsc[e1] : 0.0f;
            #define DECODE(IDX, B)                                            \
            {                                                                 \
                float x1 = rois[(IDX) * 5 + 1], y1 = rois[(IDX) * 5 + 2];     \
                float x2 = rois[(IDX) * 5 + 3], y2 = rois[(IDX) * 5 + 4];     \
                const float* dp = &bbox_pred[(IDX) * 84 + cls * 4];           \
                float d0 = dp[0], d1 = dp[1], d2 = dp[2], d3 = dp[3];         \
                float w = x2 - x1 + 1.0f, h = y2 - y1 + 1.0f;                 \
                float cx = x1 + 0.5f * w, cy = y1 + 0.5f * h;                 \
                float pcx = d0 * 0.1f * w + cx, pcy = d1 * 0.1f * h + cy;     \
                float pw = expf(d2 * 0.2f) * w, ph = expf(d3 * 0.2f) * h;     \
                B.x = fminf(fmaxf(pcx - 0.5f * pw, 0.0f), W - 1.0f);          \
                B.y = fminf(fmaxf(pcy - 0.5f * ph, 0.0f), H - 1.0f);          \
                B.z = fminf(fmaxf(pcx + 0.5f * pw, 0.0f), W - 1.0f);          \
                B.w = fminf(fmaxf(pcy + 0.5f * ph, 0.0f), H - 1.0f);          \
            }
            DECODE(idx0, b0)
            DECODE(idx1, b1)
            if (e0 < nv) { sbox[e0] = b0; ssc[e0] = sc0; }
            if (e1 < nv) { sbox[e1] = b1; ssc[e1] = sc1; }
        }
        __syncthreads();                             // B3b (sbox ready)

        if (wid == 0) {
            // suppressor masks S (2x u64 per lane) via shfl broadcasts — no LDS
            float ar0 = (b0.z - b0.x) * (b0.w - b0.y);
            float ar1 = (b1.z - b1.x) * (b1.w - b1.y);
            u64 S0lo = 0, S0hi = 0, S1lo = 0, S1hi = 0;
            for (int i = 0; i < nv; ++i) {
                bool hi = i >= 64;
                int src = i & 63;
                float cx1 = __shfl(hi ? b1.x : b0.x, src);
                float cy1 = __shfl(hi ? b1.y : b0.y, src);
                float cx2 = __shfl(hi ? b1.z : b0.z, src);
                float cy2 = __shfl(hi ? b1.w : b0.w, src);
                float car = __shfl(hi ? ar1 : ar0, src);
                float i0 = iou_f(cx1, cy1, cx2, cy2, car, b0.x, b0.y, b0.z, b0.w, ar0);
                float i1 = iou_f(cx1, cy1, cx2, cy2, car, b1.x, b1.y, b1.z, b1.w, ar1);
                bool sup0 = (i0 > NMS_T) && (i < lane);        // rank(slot0)=lane
                bool sup1 = (i1 > NMS_T) && (i < 64 + lane);   // rank(slot1)=64+lane
                if (i < 64) {
                    S0lo |= sup0 ? (1ULL << i) : 0ULL;
                    S1lo |= sup1 ? (1ULL << i) : 0ULL;
                } else {
                    S0hi |= sup0 ? (1ULL << (i - 64)) : 0ULL;
                    S1hi |= sup1 ? (1ULL << (i - 64)) : 0ULL;
                }
            }
            // greedy: pure ballot/VALU loop, zero memory
            bool alive0 = lane < nv, alive1 = 64 + lane < nv;
            u64 kw0 = __ballot(alive0), kw1 = __ballot(alive1);
            for (int i = 0; i < nv; ++i) {
                u64 kwi = (i < 64) ? kw0 : kw1;
                if ((kwi >> (i & 63)) & 1ULL) {
                    u64 t0 = (i < 64) ? (S0lo >> i) : (S0hi >> (i - 64));
                    u64 t1 = (i < 64) ? (S1lo >> i) : (S1hi >> (i - 64));
                    alive0 &= !(t0 & 1ULL);
                    alive1 &= !(t1 & 1ULL);
                    kw0 = __ballot(alive0);
                    kw1 = __ballot(alive1);
                }
            }
            if (lane == 0) { kwords[0] = kw0; kwords[1] = kw1; }
        } else if (wid == 1 || wid == 2) {
            // GT dedup in parallel (ranks 0-63 on wave1, 64-127 on wave2)
            int e = (wid - 1) * 64 + lane;
            bool dup = false;
            if (e < nv) {
                float4 a = sbox[e];
                float aarea = (a.z - a.x) * (a.w - a.y);
                for (int g = 0; g < ng; ++g) {
                    float4 gb = sgt[g];
                    float garea = (gb.z - gb.x) * (gb.w - gb.y);
                    dup |= iou_f(a.x, a.y, a.z, a.w, aarea,
                                 gb.x, gb.y, gb.z, gb.w, garea) > DEDUP_T;
                }
            }
            u64 wd = __ballot(dup);
            if (lane == 0) dupw[wid - 1] = wd;
        }
        __syncthreads();                             // B4

        // kept-row write (zero-fill already covered everything else)
        if (tid < NFAST && tid < nv) {
            bool kept = ((kwords[tid >> 6] >> (tid & 63)) & 1ULL) &&
                        !((dupw[tid >> 6] >> (tid & 63)) & 1ULL);
            if (kept) {
                float4 b = sbox[tid];
                float s = ssc[tid];
                float* orow = o + tid * 5;
                orow[0] = b.x; orow[1] = b.y; orow[2] = b.z; orow[3] = b.w;
                orow[4] = s;
            }
        }
        return;
    }

    // ================= FALLBACK (nv > 128): proven R6 LDS path =================
    for (int g = tid; g < ng; g += NT)
        sgt[g] = make_float4(gt_boxes[g * 5 + 0], gt_boxes[g * 5 + 1],
                             gt_boxes[g * 5 + 2], gt_boxes[g * 5 + 3]);

    // rank + decode, scatter sorted
    for (int v = tid; v < nv; v += NT) {
        int idx = vidx[v];
        float x1 = rois[idx * 5 + 1], y1 = rois[idx * 5 + 2];
        float x2 = rois[idx * 5 + 3], y2 = rois[idx * 5 + 4];
        const float* dp = &bbox_pred[idx * 84 + cls * 4];
        float d0 = dp[0], d1 = dp[1], d2 = dp[2], d3 = dp[3];
        float sc = vsc[v];
        int r = 0;
        for (int u = 0; u < nv; ++u) {
            float su = vsc[u];
            r += (su > sc) || (su == sc && u < v);
        }
        float w = x2 - x1 + 1.0f, h = y2 - y1 + 1.0f;
        float cx = x1 + 0.5f * w, cy = y1 + 0.5f * h;
        float pcx = d0 * 0.1f * w + cx, pcy = d1 * 0.1f * h + cy;
        float pw = expf(d2 * 0.2f) * w, ph = expf(d3 * 0.2f) * h;
        float4 b;
        b.x = fminf(fmaxf(pcx - 0.5f * pw, 0.0f), W - 1.0f);
        b.y = fminf(fmaxf(pcy - 0.5f * ph, 0.0f), H - 1.0f);
        b.z = fminf(fmaxf(pcx + 0.5f * pw, 0.0f), W - 1.0f);
        b.w = fminf(fmaxf(pcy + 0.5f * ph, 0.0f), H - 1.0f);
        sbox[r] = b;
        ssc[r]  = sc;
    }
    __syncthreads();

    const int NW = (nv + 63) >> 6;

    if (nv <= NVMAX) {
        const int ntask = nv * NW;
        for (int task = wid; task < ntask + NW; task += NWAVES) {
            if (task < ntask) {
                int i = task / NW;
                int w = task - i * NW;
                float4 a = sbox[i];
                float aarea = (a.z - a.x) * (a.w - a.y);
                int j = (w << 6) + lane;
                bool bit = false;
                if (j < nv && j > i) {
                    float4 bb = sbox[j];
                    float barea = (bb.z - bb.x) * (bb.w - bb.y);
                    bit = iou_f(a.x, a.y, a.z, a.w, aarea,
                                bb.x, bb.y, bb.z, bb.w, barea) > NMS_T;
                }
                u64 wd = __ballot(bit);
                if (lane == 0) supmat[i * NWMAX + w] = wd;
            } else {
                int w = task - ntask;
                int j = (w << 6) + lane;
                bool dup = false;
                if (j < nv) {
                    float4 a = sbox[j];
                    float aarea = (a.z - a.x) * (a.w - a.y);
                    for (int g = 0; g < ng; ++g) {
                        float4 gb = sgt[g];
                        float garea = (gb.z - gb.x) * (gb.w - gb.y);
                        dup |= iou_f(a.x, a.y, a.z, a.w, aarea,
                                     gb.x, gb.y, gb.z, gb.w, garea) > DEDUP_T;
                    }
                }
                u64 wd = __ballot(dup);
                if (lane == 0) dupw[w] = wd;
            }
        }
        __syncthreads();

        #define INITKW(W_) ((nv > (W_)*64) \
            ? ((nv - (W_)*64 >= 64) ? ~0ULL : ((1ULL << (nv - (W_)*64)) - 1ULL)) \
            : 0ULL)
        u64 kw0 = INITKW(0), kw1 = INITKW(1), kw2 = INITKW(2), kw3 = INITKW(3),
            kw4 = INITKW(4), kw5 = INITKW(5), kw6 = INITKW(6), kw7 = INITKW(7);

        #define APPL(C, B, AP)                                                \
        {                                                                     \
            const u64* _r = &supmat[(bbase + (B)) * NWMAX];                   \
            if ((C) < 1) kw1 &= ~(_r[1] & (AP));                              \
            if ((C) < 2) kw2 &= ~(_r[2] & (AP));                              \
            if ((C) < 3) kw3 &= ~(_r[3] & (AP));                              \
            if ((C) < 4) kw4 &= ~(_r[4] & (AP));                              \
            if ((C) < 5) kw5 &= ~(_r[5] & (AP));                              \
            if ((C) < 6) kw6 &= ~(_r[6] & (AP));                              \
            if ((C) < 7) kw7 &= ~(_r[7] & (AP));                              \
        }
        #define STEP(C, KWc)                                                  \
        if (nv > (C) * 64) {                                                  \
            const int bbase = (C) * 64;                                       \
            int lim = nv - bbase; if (lim > 64) lim = 64;                     \
            for (int b = 0; b < lim; ++b) {                                   \
                u64 r = supmat[(bbase + b) * NWMAX + (C)];                    \
                u64 ap = 0ULL - ((KWc >> b) & 1ULL);                          \
                KWc &= ~(r & ap); APPL(C, b, ap);                             \
            }                                                                 \
        }
        STEP(0, kw0) STEP(1, kw1) STEP(2, kw2) STEP(3, kw3)
        STEP(4, kw4) STEP(5, kw5) STEP(6, kw6) STEP(7, kw7)

        kw0 &= ~dupw[0]; kw1 &= ~dupw[1]; kw2 &= ~dupw[2]; kw3 &= ~dupw[3];
        kw4 &= ~dupw[4]; kw5 &= ~dupw[5]; kw6 &= ~dupw[6]; kw7 &= ~dupw[7];

        for (int t = tid; t < N_ROIS * 5; t += NT) {
            int j = t / 5, comp = t - 5 * j;
            int wsel = j >> 6;
            u64 myw = wsel == 0 ? kw0 : wsel == 1 ? kw1 : wsel == 2 ? kw2 :
                      wsel == 3 ? kw3 : wsel == 4 ? kw4 : wsel == 5 ? kw5 :
                      wsel == 6 ? kw6 : wsel == 7 ? kw7 : 0ULL;
            float val = 0.0f;
            if (j < nv && ((myw >> (j & 63)) & 1ULL)) {
                float4 b = sbox[j];
                val = comp == 0 ? b.x : comp == 1 ? b.y : comp == 2 ? b.z :
                      comp == 3 ? b.w : ssc[j];
            }
            o[t] = val;
        }
    } else {
        // deep fallback (nv > 512): barrier-per-row greedy
        for (int t = tid; t < nv; t += NT) keepb[t] = 1;
        for (int i = 0; i < nv; ++i) {
            __syncthreads();
            if (keepb[i]) {
                float4 a = sbox[i];
                float aarea = (a.z - a.x) * (a.w - a.y);
                for (int j = i + 1 + tid; j < nv; j += NT) {
                    if (keepb[j]) {
                        float4 bb = sbox[j];
                        float barea = (bb.z - bb.x) * (bb.w - bb.y);
                        if (iou_f(a.x, a.y, a.z, a.w, aarea,
                                  bb.x, bb.y, bb.z, bb.w, barea) > NMS_T)
                            keepb[j] = 0;
                    }
                }
            }
        }
        __syncthreads();
        for (int v = tid; v < nv; v += NT) {
            bool kept = keepb[v] != 0;
            if (kept) {
                float4 a = sbox[v];
                float aarea = (a.z - a.x) * (a.w - a.y);
                bool dup = false;
                for (int g = 0; g < ng; ++g) {
                    float4 gb = sgt[g];
                    float garea = (gb.z - gb.x) * (gb.w - gb.y);
                    dup |= iou_f(a.x, a.y, a.z, a.w, aarea,
                                 gb.x, gb.y, gb.z, gb.w, garea) > DEDUP_T;
                }
                kept = !dup;
            }
            keepb[v] = kept ? 1 : 0;
        }
        __syncthreads();
        for (int t = tid; t < N_ROIS * 5; t += NT) {
            int j = t / 5, comp = t - 5 * j;
            float val = 0.0f;
            if (j < nv && keepb[j]) {
                float4 b = sbox[j];
                val = comp == 0 ? b.x : comp == 1 ? b.y : comp == 2 ? b.z :
                      comp == 3 ? b.w : ssc[j];
            }
            o[t] = val;
        }
    }
}

extern "C" void kernel_launch(void* const* d_in, const int* in_sizes, int n_in,
                              void* d_out, int out_size, void* d_ws, size_t ws_size,
                              hipStream_t stream) {
    const float* rois      = (const float*)d_in[0];
    const float* cls_prob  = (const float*)d_in[1];
    const float* bbox_pred = (const float*)d_in[2];
    const float* im_info   = (const float*)d_in[3];
    const float* gt        = (const float*)d_in[4];
    const int*   nb        = (const int*)d_in[5];
    float* out = (float*)d_out;

    detect_kernel<<<dim3(N_CLS_OUT), dim3(NT), 0, stream>>>(
        rois, cls_prob, bbox_pred, im_info, gt, nb, out);
}